// Round 6
// baseline (76.901 us; speedup 1.0000x reference)
//
#include <hip/hip_runtime.h>

#define NG 20          // NUM_GAUSSIANS
#define NL 80          // NUM_LETTERS
#define HS 400         // HIDDEN_SIZE
#define ASCALE 0.05f   // ATTENTION_SCALE
#define BB 1024        // B
#define UU 1024        // U
#define LOG2E 1.4426950408889634f

// ---------------- Kernel A: params = transform(y0 @ W.T + bias) -------------
// 256 blocks x 256 threads, 4 batch rows per block.
// Lane (j,p): j = tid>>2 in [0,60), p = tid&3 splits K=400 into 4x100.
// W slice cached in registers (25 float4) and reused across the 4 rows ->
// W L2 traffic = 256 blocks * 96KB = 24MB (was 96MB when fused per-row).
// Writes params[row][60] = { la[20] = val*log2e, b2[20] = exp(val)*log2e,
// k[20] = exp(val)*scale + prevk } to d_ws, plus k_out (real output).
__global__ __launch_bounds__(256, 2) void param_kernel(
    const float* __restrict__ y0,      // [B,H]
    const float* __restrict__ prevk,   // [B,N]
    const float* __restrict__ W,       // [3N,H]
    const float* __restrict__ bias,    // [3N]
    float* __restrict__ params,        // [B,60] (workspace)
    float* __restrict__ k_out)         // [B,NG]
{
    const int rb  = blockIdx.x * 4;
    const int tid = threadIdx.x;

    __shared__ float yrow[4][HS];

    // stage 4 y0 rows: 1600 floats = 400 float4
    for (int i = tid; i < 4 * HS / 4; i += 256) {
        reinterpret_cast<float4*>(&yrow[0][0])[i] =
            reinterpret_cast<const float4*>(y0 + rb * HS)[i];
    }
    __syncthreads();

    if (tid < 3 * NG * 4) {                 // 240 active threads
        const int j = tid >> 2;
        const int p = tid & 3;
        float4 wreg[25];
        const float4* wr = reinterpret_cast<const float4*>(W + j * HS + p * 100);
        #pragma unroll
        for (int i = 0; i < 25; ++i) wreg[i] = wr[i];
        const float bj = bias[j];

        #pragma unroll
        for (int r = 0; r < 4; ++r) {
            const float4* yr = reinterpret_cast<const float4*>(&yrow[r][p * 100]);
            float s = 0.f;
            #pragma unroll
            for (int i = 0; i < 25; ++i) {
                const float4 w4 = wreg[i];
                const float4 y4 = yr[i];
                s += w4.x * y4.x + w4.y * y4.y + w4.z * y4.z + w4.w * y4.w;
            }
            s += __shfl_down(s, 1, 4);
            s += __shfl_down(s, 2, 4);
            if (p == 0) {
                const int row = rb + r;
                const float val = s + bj;
                float outv;
                if (j < NG) {
                    outv = val * LOG2E;                         // log2(a)
                } else if (j < 2 * NG) {
                    outv = __expf(val) * LOG2E;                 // b * log2e
                } else {
                    const int g = j - 2 * NG;
                    outv = __expf(val) * ASCALE + prevk[row * NG + g];
                    k_out[row * NG + g] = outv;
                }
                params[row * 60 + j] = outv;
            }
        }
    }
}

// ---------------- Kernel B: phi + scatter ------------------------------------
// One block per batch row, 256 threads, 4 consecutive u per thread.
// Params read with wave-uniform addresses -> scalar-load path, ~240B/block.
__global__ __launch_bounds__(256, 4) void window_kernel(
    const int*   __restrict__ text,    // [B,U]
    const int*   __restrict__ tlen,    // [B]
    const float* __restrict__ params,  // [B,60]
    float* __restrict__ w_t,           // [B,NL]
    float* __restrict__ phi_out)       // [B,U]
{
    const int b   = blockIdx.x;
    const int tid = threadIdx.x;

    const int4 letters = reinterpret_cast<const int4*>(text + b * UU)[tid];
    const int  len     = tlen[b];

    __shared__ float wloc[NL];
    if (tid < NL) wloc[tid] = 0.f;

    const float* pp = params + b * 60;
    float la[NG], b2[NG], kg[NG];
    #pragma unroll
    for (int n = 0; n < NG; ++n) {
        la[n] = pp[n];
        b2[n] = pp[NG + n];
        kg[n] = pp[2 * NG + n];
    }
    __syncthreads();

    const int u0 = tid * 4;
    float s0 = 0.f, s1 = 0.f, s2 = 0.f, s3 = 0.f;
    if (u0 < len) {
        const float uf = (float)u0;
        #pragma unroll
        for (int n = 0; n < NG; ++n) {
            const float d0 = kg[n] - uf;
            const float d1 = d0 - 1.f;
            const float d2 = d0 - 2.f;
            const float d3 = d0 - 3.f;
            s0 += __builtin_amdgcn_exp2f(__builtin_fmaf(-b2[n] * d0, d0, la[n]));
            s1 += __builtin_amdgcn_exp2f(__builtin_fmaf(-b2[n] * d1, d1, la[n]));
            s2 += __builtin_amdgcn_exp2f(__builtin_fmaf(-b2[n] * d2, d2, la[n]));
            s3 += __builtin_amdgcn_exp2f(__builtin_fmaf(-b2[n] * d3, d3, la[n]));
        }
        if (u0 + 1 >= len) s1 = 0.f;
        if (u0 + 2 >= len) s2 = 0.f;
        if (u0 + 3 >= len) s3 = 0.f;
    }
    float4 phi4; phi4.x = s0; phi4.y = s1; phi4.z = s2; phi4.w = s3;
    reinterpret_cast<float4*>(phi_out + b * UU)[tid] = phi4;

    if (s0 != 0.f) atomicAdd(&wloc[letters.x], s0);
    if (s1 != 0.f) atomicAdd(&wloc[letters.y], s1);
    if (s2 != 0.f) atomicAdd(&wloc[letters.z], s2);
    if (s3 != 0.f) atomicAdd(&wloc[letters.w], s3);
    __syncthreads();

    if (tid < NL) w_t[b * NL + tid] = wloc[tid];
}

extern "C" void kernel_launch(void* const* d_in, const int* in_sizes, int n_in,
                              void* d_out, int out_size, void* d_ws, size_t ws_size,
                              hipStream_t stream) {
    const int*   text  = (const int*)  d_in[0];
    const int*   tlen  = (const int*)  d_in[1];
    const float* y0    = (const float*)d_in[2];
    const float* prevk = (const float*)d_in[3];
    const float* W     = (const float*)d_in[4];
    const float* bias  = (const float*)d_in[5];

    float* out    = (float*)d_out;
    float* w_t    = out;                          // [B, NL]
    float* k_out  = out + BB * NL;                // [B, NG]
    float* phi    = out + BB * NL + BB * NG;      // [B, U]
    float* params = (float*)d_ws;                 // [B, 60]

    hipLaunchKernelGGL(param_kernel, dim3(BB / 4), dim3(256), 0, stream,
                       y0, prevk, W, bias, params, k_out);
    hipLaunchKernelGGL(window_kernel, dim3(BB), dim3(256), 0, stream,
                       text, tlen, params, w_t, phi);
}